// Round 10
// baseline (140.700 us; speedup 1.0000x reference)
//
#include <hip/hip_runtime.h>
#include <math.h>

#define GAMMA 0.25f
constexpr int B_ = 8, Q_ = 64, N_ = 8192, K_ = 512, C_ = 256;

typedef __attribute__((ext_vector_type(8))) short bf16x8;
typedef __attribute__((ext_vector_type(4))) short short4v;
typedef __attribute__((ext_vector_type(4))) float f32x4;

static __device__ inline short f2bf(float x) {   // RNE float->bf16 bits
    union { float f; unsigned u; } v; v.f = x;
    unsigned r = (v.u + 0x7fffu + ((v.u >> 16) & 1u)) >> 16;
    return (short)r;
}
static __device__ inline float bf2f(short h) {
    union { unsigned u; float f; } v; v.u = ((unsigned)(unsigned short)h) << 16;
    return v.f;
}

// ---------------------------------------------------------------------------
// prep: emb fp32[512][64] -> bf16 embB[512][64] + e2[k]=||bf16(emb_k)||^2 in ws.
// ---------------------------------------------------------------------------
__global__ __launch_bounds__(256) void prep_kernel(const float* __restrict__ emb,
                                                   short* __restrict__ embB,
                                                   float* __restrict__ e2g)
{
    const int r = blockIdx.x * 256 + threadIdx.x;
    if (r >= K_) return;
    const float4* src = (const float4*)(emb + r * Q_);
    short4v* dst = (short4v*)(embB + r * Q_);
    float s = 0.f;
    #pragma unroll
    for (int i = 0; i < 16; ++i) {
        const float4 v = src[i];
        short4v h;
        h[0] = f2bf(v.x); h[1] = f2bf(v.y); h[2] = f2bf(v.z); h[3] = f2bf(v.w);
        dst[i] = h;
        #pragma unroll
        for (int j = 0; j < 4; ++j) { const float a = bf2f(h[j]); s = fmaf(a, a, s); }
    }
    e2g[r] = s;
}

// ---------------------------------------------------------------------------
// mega: R8 structure (3072 blocks, role by bid%3; CACHED loads — R9's nt
// loads regressed 123.7->130.8, reverted). Change this round: each block
// finishes with ONE atomicAdd(out) instead of partial writes + reduce
// dispatch (R0/R1 proved atomics == partials+reduce here). 2-dispatch total.
// ---------------------------------------------------------------------------
__global__ __launch_bounds__(256) void mega_kernel(
    const float* __restrict__ ze, const float* __restrict__ qp,
    const int* __restrict__ tgt, const short* __restrict__ embB,
    const float* __restrict__ e2g, float* __restrict__ out)
{
    __shared__ f32x4 sh4[(64 * 68 + 256) / 4];   // 18.4 KB (VQ needs it all)
    const int bid  = blockIdx.x;
    const int tid  = threadIdx.x;
    const int lane = tid & 63;
    const int w    = tid >> 6;

    if (bid % 3 != 0) {
        // ================= CE role (2048 blocks) =================
        const int cbid = bid - bid / 3 - 1;      // 0..2047, dense
        f32x4* parts = sh4;                      // [32]

        const int g    = lane & 7;               // item group (4 items)
        const int c0   = lane >> 3;              // class subgroup (8)

        const int base = cbid * 32;              // 32-aligned => b uniform
        const int b    = base >> 13;
        const int n0   = base & (N_ - 1);
        const float* qpb = qp + (size_t)b * C_ * N_;
        const float* qpn = qpb + n0 + g * 4;
        const int cbase  = w * 64 + c0 * 8;

        float4 v[8];
        #pragma unroll
        for (int j = 0; j < 8; ++j)
            v[j] = *(const float4*)(qpn + (size_t)(cbase + j) * N_);

        float xts[4] = {0.f, 0.f, 0.f, 0.f};
        if ((w == 0) && (lane < 8)) {
            #pragma unroll
            for (int j = 0; j < 4; ++j) {
                const int t = tgt[base + lane * 4 + j];
                xts[j] = qpb[(size_t)t * N_ + n0 + lane * 4 + j];
            }
        }

        f32x4 acc = {0.f, 0.f, 0.f, 0.f};
        #pragma unroll
        for (int j = 0; j < 8; ++j) {
            acc[0] += __expf(v[j].x); acc[1] += __expf(v[j].y);
            acc[2] += __expf(v[j].z); acc[3] += __expf(v[j].w);
        }
        #pragma unroll
        for (int r = 0; r < 4; ++r) {            // reduce over c0 (lane bits 3,4,5)
            acc[r] += __shfl_xor(acc[r], 8, 64);
            acc[r] += __shfl_xor(acc[r], 16, 64);
            acc[r] += __shfl_xor(acc[r], 32, 64);
        }
        if (c0 == 0) parts[w * 8 + g] = acc;
        __syncthreads();

        if (w == 0) {
            float loss = 0.f;
            if (lane < 8) {
                const f32x4 tot = (parts[lane] + parts[8 + lane]) +
                                  (parts[16 + lane] + parts[24 + lane]);
                #pragma unroll
                for (int j = 0; j < 4; ++j) loss += __logf(tot[j]) - xts[j];
            }
            loss += __shfl_down(loss, 4, 64);
            loss += __shfl_down(loss, 2, 64);
            loss += __shfl_down(loss, 1, 64);
            if (lane == 0) atomicAdd(out, loss);
        }
    } else {
        // ================= VQ role (1024 blocks) =================
        const int vbid = bid / 3;                // 0..1023
        float* smem = (float*)sh4;
        float* minb = smem + 64 * 68;

        const int n16  = lane & 15;
        const int quad = lane >> 4;

        const int base = vbid * 64;              // 64-aligned => b uniform
        const int b    = base >> 13;
        const int n0   = base & (N_ - 1);
        const float* zb = ze + (size_t)b * Q_ * N_;

        // ---- issue ze tile loads: thread owns q=tid>>2, quarter pt=tid&3 ----
        const int q  = tid >> 2;
        const int pt = tid & 3;
        const float* zq = zb + (size_t)q * N_ + n0 + pt * 4;
        float4 st[4];
        #pragma unroll
        for (int i = 0; i < 4; ++i)
            st[i] = *(const float4*)(zq + i * 16);

        // ---- issue B tiles + e2 while ze lands (reused data, cached) ----
        const short* bb = embB + (w * 128 + n16) * Q_ + quad * 8;
        bf16x8 Bv[8][2];
        float  e2v[8];
        #pragma unroll
        for (int t = 0; t < 8; ++t) {
            Bv[t][0] = *(const bf16x8*)(bb + t * 16 * Q_);
            Bv[t][1] = *(const bf16x8*)(bb + t * 16 * Q_ + 32);
            e2v[t]   = e2g[w * 128 + t * 16 + n16];
        }

        // ---- write ze to LDS transposed [n][q] ----
        #pragma unroll
        for (int i = 0; i < 4; ++i) {
            const int nn = i * 16 + pt * 4;
            smem[(nn + 0) * 68 + q] = st[i].x;
            smem[(nn + 1) * 68 + q] = st[i].y;
            smem[(nn + 2) * 68 + q] = st[i].z;
            smem[(nn + 3) * 68 + q] = st[i].w;
        }
        __syncthreads();

        // ---- fragments from LDS (2 x b128 each) + zsq + bf16(-2x) ----
        bf16x8 afrag[4][2];
        float zsq = 0.f;
        #pragma unroll
        for (int u = 0; u < 4; ++u) {
            #pragma unroll
            for (int s = 0; s < 2; ++s) {
                const float* bse = smem + (u * 16 + n16) * 68 + s * 32 + quad * 8;
                const f32x4 x0 = *(const f32x4*)(bse);
                const f32x4 x1 = *(const f32x4*)(bse + 4);
                #pragma unroll
                for (int j = 0; j < 4; ++j) {
                    zsq = fmaf(x0[j], x0[j], zsq);
                    afrag[u][s][j] = f2bf(-2.f * x0[j]);
                }
                #pragma unroll
                for (int j = 0; j < 4; ++j) {
                    zsq = fmaf(x1[j], x1[j], zsq);
                    afrag[u][s][4 + j] = f2bf(-2.f * x1[j]);
                }
            }
        }

        // ---- 8 tiles back-to-back from registers ----
        f32x4 best[4];
        #pragma unroll
        for (int u = 0; u < 4; ++u) best[u] = (f32x4){1e30f, 1e30f, 1e30f, 1e30f};

        #pragma unroll
        for (int t = 0; t < 8; ++t) {
            const f32x4 ce2 = {e2v[t], e2v[t], e2v[t], e2v[t]};
            #pragma unroll
            for (int u = 0; u < 4; ++u) {        // 4 independent MFMA chains
                f32x4 a = __builtin_amdgcn_mfma_f32_16x16x32_bf16(afrag[u][0], Bv[t][0], ce2, 0, 0, 0);
                a       = __builtin_amdgcn_mfma_f32_16x16x32_bf16(afrag[u][1], Bv[t][1], a,   0, 0, 0);
                #pragma unroll
                for (int r = 0; r < 4; ++r) best[u][r] = fminf(best[u][r], a[r]);
            }
        }

        // ---- min over this wave's 16 cw columns; stash per-item mins ----
        #pragma unroll
        for (int m = 1; m < 16; m <<= 1) {
            #pragma unroll
            for (int u = 0; u < 4; ++u) {
                #pragma unroll
                for (int r = 0; r < 4; ++r)
                    best[u][r] = fminf(best[u][r], __shfl_xor(best[u][r], m, 64));
            }
        }
        if (n16 == 0) {                          // lanes 0,16,32,48
            #pragma unroll
            for (int u = 0; u < 4; ++u) {
                #pragma unroll
                for (int r = 0; r < 4; ++r)      // item = u*16 + quad*4 + r
                    minb[w * 64 + u * 16 + quad * 4 + r] = best[u][r];
            }
        }
        __syncthreads();

        // ---- finalize (wave 0; zsq identical across waves) ----
        if (w == 0) {
            const float mn = fminf(fminf(minb[lane], minb[64 + lane]),
                                   fminf(minb[128 + lane], minb[192 + lane]));
            float val = 1.25f * (mn + zsq);
            #pragma unroll
            for (int off = 32; off > 0; off >>= 1) val += __shfl_down(val, off, 64);
            if (lane == 0) atomicAdd(out, val);
        }
    }
}

extern "C" void kernel_launch(void* const* d_in, const int* in_sizes, int n_in,
                              void* d_out, int out_size, void* d_ws, size_t ws_size,
                              hipStream_t stream) {
    const float* ze  = (const float*)d_in[0];
    const float* emb = (const float*)d_in[1];
    const float* qp  = (const float*)d_in[2];
    const int*   tgt = (const int*)d_in[3];
    float* out = (float*)d_out;

    short* embB = (short*)d_ws;                                  // 64 KB
    float* e2g  = (float*)((char*)d_ws + 65536);                 // +2 KB

    hipMemsetAsync(out, 0, sizeof(float), stream);
    prep_kernel<<<2, 256, 0, stream>>>(emb, embB, e2g);
    mega_kernel<<<3072, 256, 0, stream>>>(ze, qp, tgt, embB, e2g, out);
}

// Round 11
// 125.028 us; speedup vs baseline: 1.1254x; 1.1254x over previous
//
#include <hip/hip_runtime.h>
#include <math.h>

#define GAMMA 0.25f
constexpr int B_ = 8, Q_ = 64, N_ = 8192, K_ = 512, C_ = 256;

typedef __attribute__((ext_vector_type(8))) short bf16x8;
typedef __attribute__((ext_vector_type(4))) short short4v;
typedef __attribute__((ext_vector_type(4))) float f32x4;

static __device__ inline short f2bf(float x) {   // RNE float->bf16 bits
    union { float f; unsigned u; } v; v.f = x;
    unsigned r = (v.u + 0x7fffu + ((v.u >> 16) & 1u)) >> 16;
    return (short)r;
}
static __device__ inline float bf2f(short h) {
    union { unsigned u; float f; } v; v.u = ((unsigned)(unsigned short)h) << 16;
    return v.f;
}

// ---------------------------------------------------------------------------
// prep: emb fp32[512][64] -> bf16 embB[512][64] + e2[k]=||bf16(emb_k)||^2 in ws.
// ---------------------------------------------------------------------------
__global__ __launch_bounds__(256) void prep_kernel(const float* __restrict__ emb,
                                                   short* __restrict__ embB,
                                                   float* __restrict__ e2g)
{
    const int r = blockIdx.x * 256 + threadIdx.x;
    if (r >= K_) return;
    const float4* src = (const float4*)(emb + r * Q_);
    short4v* dst = (short4v*)(embB + r * Q_);
    float s = 0.f;
    #pragma unroll
    for (int i = 0; i < 16; ++i) {
        const float4 v = src[i];
        short4v h;
        h[0] = f2bf(v.x); h[1] = f2bf(v.y); h[2] = f2bf(v.z); h[3] = f2bf(v.w);
        dst[i] = h;
        #pragma unroll
        for (int j = 0; j < 4; ++j) { const float a = bf2f(h[j]); s = fmaf(a, a, s); }
    }
    e2g[r] = s;
}

// ---------------------------------------------------------------------------
// mega v3: 512 PERSISTENT blocks (2/CU), software-pipelined.
// R10 counters: mega = 50us, FETCH 41MB @ 847GB/s, VALUBusy 13%, Occ 12%
// (~1 block/CU) -> latency-serialized block restarts, nothing busy.
// Fix: blocks own tile SEQUENCES; next tile's loads issue while current
// computes, so latency hides inside each wave instead of across blocks.
//   CE (bid<256): 8 tiles x 32 items, reg double-buffer, 1 barrier/block.
//   VQ (bid>=256): 4 tiles x 64 items, Bv/e2v hoisted (tile-invariant),
//     LDS double-buffer staging, per-tile minb slots -> 1 barrier/tile.
// Per-item math bit-identical to verified R7/R8. Partials (no atomics:
// R10 showed 3072 same-address atomics cost ~9us + dur regression).
// ---------------------------------------------------------------------------
__global__ __launch_bounds__(256) void mega_kernel(
    const float* __restrict__ ze, const float* __restrict__ qp,
    const int* __restrict__ tgt, const short* __restrict__ embB,
    const float* __restrict__ e2g,
    float* __restrict__ cePart, float* __restrict__ vqPart)
{
    __shared__ f32x4 sh4[2432];              // 38.9 KB (VQ: 2x4352 + 1024 fl)
    const int bid  = blockIdx.x;
    const int tid  = threadIdx.x;
    const int lane = tid & 63;
    const int w    = tid >> 6;

    if (bid < 256) {
        // ================= CE role: 256 items, 8 pipelined tiles ===========
        f32x4* ceparts = sh4;                        // [8][4][8] f32x4 = 4KB
        float* xb      = (float*)(sh4 + 256);        // [256]

        const int base0 = bid * 256;                 // 256-aligned => b uniform
        const int b     = base0 >> 13;
        const int n0    = base0 & (N_ - 1);
        const float* qpb = qp + (size_t)b * C_ * N_;

        // target gather: issued first (dependent 2-load chain), used at end
        const int tg = tgt[base0 + tid];
        const float xval = qpb[(size_t)tg * N_ + n0 + tid];

        const int g  = lane & 7;                     // item group (4 items)
        const int c0 = lane >> 3;                    // class subgroup
        const int cbase = w * 64 + c0 * 8;
        const float* qpn = qpb + n0 + g * 4;

        float4 v[2][8];
        #pragma unroll
        for (int j = 0; j < 8; ++j)
            v[0][j] = *(const float4*)(qpn + (size_t)(cbase + j) * N_);

        #pragma unroll
        for (int t = 0; t < 8; ++t) {                // full unroll: all idx static
            if (t < 7) {
                #pragma unroll
                for (int j = 0; j < 8; ++j)
                    v[(t + 1) & 1][j] = *(const float4*)(qpn + (t + 1) * 32 +
                                                         (size_t)(cbase + j) * N_);
            }
            f32x4 acc = {0.f, 0.f, 0.f, 0.f};
            #pragma unroll
            for (int j = 0; j < 8; ++j) {
                const float4 x = v[t & 1][j];
                acc[0] += __expf(x.x); acc[1] += __expf(x.y);
                acc[2] += __expf(x.z); acc[3] += __expf(x.w);
            }
            #pragma unroll
            for (int r = 0; r < 4; ++r) {            // fold c0 (lane bits 3,4,5)
                acc[r] += __shfl_xor(acc[r], 8, 64);
                acc[r] += __shfl_xor(acc[r], 16, 64);
                acc[r] += __shfl_xor(acc[r], 32, 64);
            }
            if (c0 == 0) ceparts[t * 32 + w * 8 + g] = acc;
        }
        xb[tid] = xval;
        __syncthreads();                             // the ONLY CE barrier

        if (tid < 64) {                              // wave0: 64 (t,g) pairs
            const int t = tid >> 3, gg = tid & 7;
            const f32x4 tot = (ceparts[t * 32 + gg] + ceparts[t * 32 + 8 + gg]) +
                              (ceparts[t * 32 + 16 + gg] + ceparts[t * 32 + 24 + gg]);
            float loss = 0.f;
            #pragma unroll
            for (int j = 0; j < 4; ++j)
                loss += __logf(tot[j]) - xb[t * 32 + gg * 4 + j];
            #pragma unroll
            for (int off = 32; off > 0; off >>= 1) loss += __shfl_down(loss, off, 64);
            if (tid == 0) cePart[bid] = loss;
        }
    } else {
        // ================= VQ role: 4 pipelined tiles of 64 items ==========
        const int vbid  = bid - 256;                 // 0..255
        float* zebuf0 = (float*)sh4;                 // [64][68]
        float* zebuf1 = zebuf0 + 64 * 68;
        float* minb   = zebuf0 + 2 * 64 * 68;        // [4][256]

        const int n16  = lane & 15;
        const int quad = lane >> 4;
        const int base0 = vbid * 256;                // b uniform over 4 tiles
        const int b     = base0 >> 13;
        const int n0    = base0 & (N_ - 1);
        const float* zb = ze + (size_t)b * Q_ * N_;

        const int q  = tid >> 2;
        const int pt = tid & 3;
        const float* zq = zb + (size_t)q * N_ + n0 + pt * 4;   // tile t: +t*64

        // ---- tile0 staging loads first (critical path) ----
        float4 st[4];
        #pragma unroll
        for (int i = 0; i < 4; ++i)
            st[i] = *(const float4*)(zq + i * 16);

        // ---- Bv/e2v hoisted: invariant across tiles (L2-hot) ----
        const short* bb = embB + (w * 128 + n16) * Q_ + quad * 8;
        bf16x8 Bv[8][2];
        float  e2v[8];
        #pragma unroll
        for (int t = 0; t < 8; ++t) {
            Bv[t][0] = *(const bf16x8*)(bb + t * 16 * Q_);
            Bv[t][1] = *(const bf16x8*)(bb + t * 16 * Q_ + 32);
            e2v[t]   = e2g[w * 128 + t * 16 + n16];
        }

        // ---- write tile0 to buf0 transposed ----
        #pragma unroll
        for (int i = 0; i < 4; ++i) {
            const int nn = i * 16 + pt * 4;
            zebuf0[(nn + 0) * 68 + q] = st[i].x;
            zebuf0[(nn + 1) * 68 + q] = st[i].y;
            zebuf0[(nn + 2) * 68 + q] = st[i].z;
            zebuf0[(nn + 3) * 68 + q] = st[i].w;
        }
        __syncthreads();

        float zs[4];
        #pragma unroll
        for (int t = 0; t < 4; ++t) {                // full unroll: static idx
            float* bufc = (t & 1) ? zebuf1 : zebuf0;
            float* bufn = (t & 1) ? zebuf0 : zebuf1;

            if (t < 3) {                             // issue next tile's loads
                #pragma unroll
                for (int i = 0; i < 4; ++i)
                    st[i] = *(const float4*)(zq + (t + 1) * 64 + i * 16);
            }

            // fragments + zsq from bufc (identical math to R7)
            bf16x8 afrag[4][2];
            float zsq = 0.f;
            #pragma unroll
            for (int u = 0; u < 4; ++u) {
                #pragma unroll
                for (int s = 0; s < 2; ++s) {
                    const float* bse = bufc + (u * 16 + n16) * 68 + s * 32 + quad * 8;
                    const f32x4 x0 = *(const f32x4*)(bse);
                    const f32x4 x1 = *(const f32x4*)(bse + 4);
                    #pragma unroll
                    for (int j = 0; j < 4; ++j) {
                        zsq = fmaf(x0[j], x0[j], zsq);
                        afrag[u][s][j] = f2bf(-2.f * x0[j]);
                    }
                    #pragma unroll
                    for (int j = 0; j < 4; ++j) {
                        zsq = fmaf(x1[j], x1[j], zsq);
                        afrag[u][s][4 + j] = f2bf(-2.f * x1[j]);
                    }
                }
            }
            zs[t] = zsq;

            f32x4 best[4];
            #pragma unroll
            for (int u = 0; u < 4; ++u) best[u] = (f32x4){1e30f, 1e30f, 1e30f, 1e30f};
            #pragma unroll
            for (int tt = 0; tt < 8; ++tt) {
                const f32x4 ce2 = {e2v[tt], e2v[tt], e2v[tt], e2v[tt]};
                #pragma unroll
                for (int u = 0; u < 4; ++u) {
                    f32x4 a = __builtin_amdgcn_mfma_f32_16x16x32_bf16(afrag[u][0], Bv[tt][0], ce2, 0, 0, 0);
                    a       = __builtin_amdgcn_mfma_f32_16x16x32_bf16(afrag[u][1], Bv[tt][1], a,   0, 0, 0);
                    #pragma unroll
                    for (int r = 0; r < 4; ++r) best[u][r] = fminf(best[u][r], a[r]);
                }
            }
            #pragma unroll
            for (int m = 1; m < 16; m <<= 1) {
                #pragma unroll
                for (int u = 0; u < 4; ++u) {
                    #pragma unroll
                    for (int r = 0; r < 4; ++r)
                        best[u][r] = fminf(best[u][r], __shfl_xor(best[u][r], m, 64));
                }
            }
            if (n16 == 0) {                          // per-tile minb slots
                #pragma unroll
                for (int u = 0; u < 4; ++u) {
                    #pragma unroll
                    for (int r = 0; r < 4; ++r)
                        minb[t * 256 + w * 64 + u * 16 + quad * 4 + r] = best[u][r];
                }
            }

            if (t < 3) {                             // stage next into bufn;
                #pragma unroll                       // bufn's readers finished
                for (int i = 0; i < 4; ++i) {        // at barrier(t-1)
                    const int nn = i * 16 + pt * 4;
                    bufn[(nn + 0) * 68 + q] = st[i].x;
                    bufn[(nn + 1) * 68 + q] = st[i].y;
                    bufn[(nn + 2) * 68 + q] = st[i].z;
                    bufn[(nn + 3) * 68 + q] = st[i].w;
                }
            }
            __syncthreads();                         // 1 barrier per tile
        }

        if (w == 0) {                                // all minb slots final
            float vsum = 0.f;
            #pragma unroll
            for (int t = 0; t < 4; ++t) {
                const float mn = fminf(fminf(minb[t * 256 + lane], minb[t * 256 + 64 + lane]),
                                       fminf(minb[t * 256 + 128 + lane], minb[t * 256 + 192 + lane]));
                vsum += 1.25f * (mn + zs[t]);
            }
            #pragma unroll
            for (int off = 32; off > 0; off >>= 1) vsum += __shfl_down(vsum, off, 64);
            if (lane == 0) vqPart[vbid] = vsum;
        }
    }
}

// ---------------------------------------------------------------------------
// reduce: deterministic sum of 256 CE + 256 VQ partials -> out.
// ---------------------------------------------------------------------------
__global__ __launch_bounds__(256) void reduce_kernel(const float* __restrict__ cePart,
                                                     const float* __restrict__ vqPart,
                                                     float* __restrict__ out)
{
    __shared__ float sm[4];
    const int tid = threadIdx.x;
    float s = cePart[tid] + vqPart[tid];
    #pragma unroll
    for (int off = 32; off > 0; off >>= 1) s += __shfl_down(s, off, 64);
    if ((tid & 63) == 0) sm[tid >> 6] = s;
    __syncthreads();
    if (tid == 0) out[0] = (sm[0] + sm[1]) + (sm[2] + sm[3]);
}

extern "C" void kernel_launch(void* const* d_in, const int* in_sizes, int n_in,
                              void* d_out, int out_size, void* d_ws, size_t ws_size,
                              hipStream_t stream) {
    const float* ze  = (const float*)d_in[0];
    const float* emb = (const float*)d_in[1];
    const float* qp  = (const float*)d_in[2];
    const int*   tgt = (const int*)d_in[3];
    float* out = (float*)d_out;

    short* embB   = (short*)d_ws;                                // 64 KB
    float* e2g    = (float*)((char*)d_ws + 65536);               // +2 KB
    float* cePart = (float*)((char*)d_ws + 67584);               // +1 KB
    float* vqPart = (float*)((char*)d_ws + 68608);               // +1 KB

    prep_kernel<<<2, 256, 0, stream>>>(emb, embB, e2g);
    mega_kernel<<<512, 256, 0, stream>>>(ze, qp, tgt, embB, e2g, cePart, vqPart);
    reduce_kernel<<<1, 256, 0, stream>>>(cePart, vqPart, out);
}